// Round 2
// baseline (1078.816 us; speedup 1.0000x reference)
//
#include <hip/hip_runtime.h>
#include <hip/hip_bf16.h>
#include <math.h>

// FraudGNN: 2-layer GraphSAGE (mean aggr) + FC + sigmoid on MI355X (gfx950).
// N=100000, E=1600000, dims 64 -> 128 -> 64 -> 1. ALL float tensors are fp32
// (reference dtype); edge_index is int32. Internal h1 stored bf16.
//
// Pipeline: CSR-by-dst build (hist + 1-block scan + fill) -> fused
// {gather-mean + dense update} per layer, wave-per-node, no feature atomics.

#define IN_C 64
#define HID 128
#define HID2 64

// ---------------- CSR build ----------------

__global__ void hist_kernel(const int* __restrict__ ei, int* __restrict__ deg, int E) {
    int e = blockIdx.x * 256 + threadIdx.x;
    if (e < E) atomicAdd(&deg[ei[E + e]], 1);
}

__global__ __launch_bounds__(1024) void scan_kernel(
    const int* __restrict__ deg, int* __restrict__ row_ptr,
    int* __restrict__ fill_pos, int N, int E)
{
    __shared__ int sums[1024];
    int tid = threadIdx.x;
    int chunk = (N + 1023) >> 10;
    int lo = tid * chunk;
    int hi = min(lo + chunk, N);
    int s = 0;
    for (int i = lo; i < hi; ++i) s += deg[i];
    sums[tid] = s;
    __syncthreads();
    for (int off = 1; off < 1024; off <<= 1) {
        int v = (tid >= off) ? sums[tid - off] : 0;
        __syncthreads();
        sums[tid] += v;
        __syncthreads();
    }
    int base = (tid == 0) ? 0 : sums[tid - 1]; // exclusive base of my chunk
    for (int i = lo; i < hi; ++i) {
        row_ptr[i] = base;
        fill_pos[i] = base;
        base += deg[i];
    }
    if (tid == 0) row_ptr[N] = E;
}

__global__ void fill_kernel(const int* __restrict__ ei, int* __restrict__ fill_pos,
                            int* __restrict__ srcs, int E) {
    int e = blockIdx.x * 256 + threadIdx.x;
    if (e >= E) return;
    int d = ei[E + e];
    int p = atomicAdd(&fill_pos[d], 1);
    srcs[p] = ei[e]; // source node id
}

// ---------------- Layer 1 (fused gather-mean + GEMM + ReLU) ----------------
// Wave per node. lane = input feature (64). Gather is 256B/row coalesced.
// Then each lane computes output channels {lane, lane+64} of
// h1 = relu(mean @ W1l + b1 + x_self @ W1r), weights streamed from L1/L2.

__global__ __launch_bounds__(256) void layer1_kernel(
    const float* __restrict__ x, const int* __restrict__ row_ptr,
    const int* __restrict__ srcs,
    const float* __restrict__ W1l, const float* __restrict__ b1,
    const float* __restrict__ W1r, __hip_bfloat16* __restrict__ h1, int N)
{
    __shared__ float sa[4][IN_C];   // mean of neighbor features
    __shared__ float sx[4][IN_C];   // self features
    int w = threadIdx.x >> 6;
    int lane = threadIdx.x & 63;
    int node = blockIdx.x * 4 + w;
    if (node < N) {
        int s0 = row_ptr[node], s1 = row_ptr[node + 1];
        float s = 0.f;
        for (int e = s0; e < s1; ++e)
            s += x[(size_t)srcs[e] * IN_C + lane];
        float d = (float)(s1 - s0);
        sa[w][lane] = (d > 0.f) ? s / d : 0.f;
        sx[w][lane] = x[(size_t)node * IN_C + lane];
    }
    __syncthreads();
    if (node >= N) return;
    int j0 = lane, j1 = lane + 64;
    float acc0 = b1[j0], acc1 = b1[j1];
#pragma unroll 8
    for (int c = 0; c < IN_C; ++c) {
        float m = sa[w][c];
        float xs = sx[w][c];
        acc0 += m * W1l[c * HID + j0] + xs * W1r[c * HID + j0];
        acc1 += m * W1l[c * HID + j1] + xs * W1r[c * HID + j1];
    }
    h1[(size_t)node * HID + j0] = __float2bfloat16(fmaxf(acc0, 0.f));
    h1[(size_t)node * HID + j1] = __float2bfloat16(fmaxf(acc1, 0.f));
}

// ---------------- Layer 2 + FC + sigmoid (fused) ----------------
// Wave per node. lane gathers bf16 feature pair (2*lane, 2*lane+1): 256B/row.
// Then lane computes output channel `lane` of layer2 (64 ch), relu, * Wfc,
// wave shuffle-reduce, sigmoid.

__global__ __launch_bounds__(256) void layer2_kernel(
    const __hip_bfloat16* __restrict__ h1, const int* __restrict__ row_ptr,
    const int* __restrict__ srcs,
    const float* __restrict__ W2l, const float* __restrict__ b2,
    const float* __restrict__ W2r, const float* __restrict__ Wfc,
    const float* __restrict__ bfc, float* __restrict__ out, int N)
{
    __shared__ float sm[4][HID];    // mean of neighbor h1
    __shared__ float ss[4][HID];    // self h1
    int w = threadIdx.x >> 6;
    int lane = threadIdx.x & 63;
    int node = blockIdx.x * 4 + w;
    if (node < N) {
        int s0 = row_ptr[node], s1 = row_ptr[node + 1];
        float a0 = 0.f, a1 = 0.f;
        for (int e = s0; e < s1; ++e) {
            const __hip_bfloat162 p =
                ((const __hip_bfloat162*)(h1 + (size_t)srcs[e] * HID))[lane];
            a0 += __bfloat162float(p.x);
            a1 += __bfloat162float(p.y);
        }
        float d = (float)(s1 - s0);
        float scale = (d > 0.f) ? 1.f / d : 0.f;
        sm[w][2 * lane]     = a0 * scale;
        sm[w][2 * lane + 1] = a1 * scale;
        const __hip_bfloat162 q =
            ((const __hip_bfloat162*)(h1 + (size_t)node * HID))[lane];
        ss[w][2 * lane]     = __bfloat162float(q.x);
        ss[w][2 * lane + 1] = __bfloat162float(q.y);
    }
    __syncthreads();
    if (node >= N) return;
    float acc = b2[lane];
#pragma unroll 8
    for (int c = 0; c < HID; ++c) {
        acc += sm[w][c] * W2l[c * HID2 + lane]
             + ss[w][c] * W2r[c * HID2 + lane];
    }
    float h2 = fmaxf(acc, 0.f) * Wfc[lane];
    for (int off = 32; off > 0; off >>= 1) h2 += __shfl_down(h2, off);
    if (lane == 0) {
        float z = h2 + bfc[0];
        out[node] = 1.f / (1.f + expf(-z));
    }
}

// ---------------- launch ----------------

static inline size_t align_up(size_t v, size_t a) { return (v + a - 1) & ~(a - 1); }

extern "C" void kernel_launch(void* const* d_in, const int* in_sizes, int n_in,
                              void* d_out, int out_size, void* d_ws, size_t ws_size,
                              hipStream_t stream) {
    const float* x   = (const float*)d_in[0];
    const int*   ei  = (const int*)d_in[1];
    const float* W1l = (const float*)d_in[2];
    const float* b1  = (const float*)d_in[3];
    const float* W1r = (const float*)d_in[4];
    const float* W2l = (const float*)d_in[5];
    const float* b2  = (const float*)d_in[6];
    const float* W2r = (const float*)d_in[7];
    const float* Wfc = (const float*)d_in[8];
    const float* bfc = (const float*)d_in[9];
    float* out = (float*)d_out;

    const int N = in_sizes[0] / IN_C;   // 100000
    const int E = in_sizes[1] / 2;      // 1600000

    // workspace layout (~33.2 MB total)
    char* ws = (char*)d_ws;
    size_t o = 0;
    int* deg      = (int*)(ws + o); o = align_up(o + (size_t)N * 4, 256);
    int* row_ptr  = (int*)(ws + o); o = align_up(o + (size_t)(N + 1) * 4, 256);
    int* fill_pos = (int*)(ws + o); o = align_up(o + (size_t)N * 4, 256);
    int* srcs     = (int*)(ws + o); o = align_up(o + (size_t)E * 4, 256);
    __hip_bfloat16* h1 = (__hip_bfloat16*)(ws + o); o = align_up(o + (size_t)N * HID * 2, 256);

    hipMemsetAsync(deg, 0, (size_t)N * 4, stream);

    int eb = (E + 255) / 256;
    hist_kernel<<<eb, 256, 0, stream>>>(ei, deg, E);
    scan_kernel<<<1, 1024, 0, stream>>>(deg, row_ptr, fill_pos, N, E);
    fill_kernel<<<eb, 256, 0, stream>>>(ei, fill_pos, srcs, E);

    int nb = (N + 3) / 4; // 4 nodes (waves) per 256-thread block
    layer1_kernel<<<nb, 256, 0, stream>>>(x, row_ptr, srcs, W1l, b1, W1r, h1, N);
    layer2_kernel<<<nb, 256, 0, stream>>>(h1, row_ptr, srcs, W2l, b2, W2r, Wfc, bfc, out, N);
}

// Round 3
// 507.299 us; speedup vs baseline: 2.1266x; 2.1266x over previous
//
#include <hip/hip_runtime.h>
#include <hip/hip_bf16.h>
#include <math.h>

// FraudGNN on MI355X: CSR build -> bf16 gather-mean (ILP-unrolled, half-wave
// per edge row) -> one fused MFMA dense kernel (H1 in LDS, pre-projected
// G=H1@W2l, S2=H1@W2r) -> gather-mean of G fused with FC+sigmoid epilogue.

#define IN_C 64
#define HID 128
#define HID2 64
#define LDA 136   // LDS row stride (elements): 272B, 16B-aligned, conflict-light

typedef short short8 __attribute__((ext_vector_type(8)));
typedef float f32x4 __attribute__((ext_vector_type(4)));

__device__ inline unsigned short bfbits(float f) {
    __hip_bfloat16 h = __float2bfloat16(f);
    return *reinterpret_cast<unsigned short*>(&h);
}
__device__ inline float bflo(unsigned u) { return __uint_as_float(u << 16); }
__device__ inline float bfhi(unsigned u) { return __uint_as_float(u & 0xffff0000u); }
__device__ inline unsigned bfpack(float a, float b) {
    return ((unsigned)bfbits(b) << 16) | (unsigned)bfbits(a);
}

// ---------------- x -> bf16 (packed pairs) ----------------
__global__ void convert_x_kernel(const float2* __restrict__ x2,
                                 unsigned* __restrict__ xbu, int n2) {
    int i = blockIdx.x * 256 + threadIdx.x;
    if (i < n2) { float2 v = x2[i]; xbu[i] = bfpack(v.x, v.y); }
}

// ---------------- CSR build ----------------
__global__ void hist_kernel(const int* __restrict__ ei, int* __restrict__ deg, int E) {
    int e = blockIdx.x * 256 + threadIdx.x;
    if (e < E) atomicAdd(&deg[ei[E + e]], 1);
}

__global__ void scanA_kernel(const int* __restrict__ deg, int* __restrict__ bsum, int N) {
    __shared__ int red[4];
    int t = threadIdx.x;
    int i = blockIdx.x * 256 + t;
    int v = (i < N) ? deg[i] : 0;
    for (int off = 1; off < 64; off <<= 1) v += __shfl_xor(v, off);
    if ((t & 63) == 0) red[t >> 6] = v;
    __syncthreads();
    if (t == 0) bsum[blockIdx.x] = red[0] + red[1] + red[2] + red[3];
}

__global__ __launch_bounds__(512) void scanB_kernel(int* __restrict__ bsum, int nb) {
    __shared__ int s[512];
    int t = threadIdx.x;
    int v = (t < nb) ? bsum[t] : 0;
    s[t] = v;
    __syncthreads();
    for (int off = 1; off < 512; off <<= 1) {
        int u = (t >= off) ? s[t - off] : 0;
        __syncthreads();
        s[t] += u;
        __syncthreads();
    }
    if (t < nb) bsum[t] = s[t] - v; // exclusive
}

__global__ void scanC_kernel(const int* __restrict__ deg, const int* __restrict__ bsum,
                             int* __restrict__ row_ptr, int* __restrict__ fill_pos,
                             int N, int E) {
    __shared__ int wsum[4];
    int t = threadIdx.x;
    int lane = t & 63, w = t >> 6;
    int i = blockIdx.x * 256 + t;
    int v = (i < N) ? deg[i] : 0;
    int x = v;
    for (int off = 1; off < 64; off <<= 1) {
        int u = __shfl_up(x, off);
        if (lane >= off) x += u;
    }
    if (lane == 63) wsum[w] = x;
    __syncthreads();
    int add = 0;
    for (int k = 0; k < w; ++k) add += wsum[k];
    int excl = bsum[blockIdx.x] + x + add - v;
    if (i < N) { row_ptr[i] = excl; fill_pos[i] = excl; }
    if (i == N - 1) row_ptr[N] = E;
}

__global__ void fill_kernel(const int* __restrict__ ei, int* __restrict__ fill_pos,
                            int* __restrict__ srcs, int E) {
    int e = blockIdx.x * 256 + threadIdx.x;
    if (e >= E) return;
    int d = ei[E + e];
    int p = atomicAdd(&fill_pos[d], 1);
    srcs[p] = ei[e];
}

// ---------------- gather-mean of xb -> M1 (bf16) ----------------
// Wave per node; half-wave handles one 128B row per load; 4x unroll = 8 edges
// (8 independent row loads) in flight.
__global__ __launch_bounds__(256) void agg1_kernel(
    const unsigned* __restrict__ xbu, const int* __restrict__ row_ptr,
    const int* __restrict__ srcs, unsigned* __restrict__ M1u, int N)
{
    int g = blockIdx.x * 256 + threadIdx.x;
    int node = g >> 6;
    if (node >= N) return;
    int lane = g & 63, hl = lane & 31, half = lane >> 5;
    int s0 = row_ptr[node], s1 = row_ptr[node + 1];
    float a0 = 0.f, a1 = 0.f;
    for (int e = s0; e < s1; e += 8) {
#pragma unroll
        for (int k = 0; k < 4; ++k) {
            int ek = e + half + 2 * k;
            bool valid = ek < s1;
            int src = srcs[valid ? ek : s0];
            unsigned u = xbu[src * 32 + hl];
            if (valid) { a0 += bflo(u); a1 += bfhi(u); }
        }
    }
    a0 += __shfl_xor(a0, 32);
    a1 += __shfl_xor(a1, 32);
    int deg = s1 - s0;
    float scale = deg > 0 ? 1.f / (float)deg : 0.f;
    if (half == 0) M1u[node * 32 + hl] = bfpack(a0 * scale, a1 * scale);
}

// ---------------- fused dense: H1 -> G, S2 (MFMA) ----------------
// Per 128-node tile: A = [M1 | bf16(x)] (128x128), B1 = [W1l ; W1r] (128x128),
// H1 = relu(A@B1 + b1) kept in LDS; then [G|S2] = H1 @ [W2l | W2r].
__global__ __launch_bounds__(256) void dense_kernel(
    const unsigned short* __restrict__ M1s, const float* __restrict__ x,
    const float* __restrict__ W1l, const float* __restrict__ b1,
    const float* __restrict__ W1r, const float* __restrict__ W2l,
    const float* __restrict__ W2r, unsigned short* __restrict__ G,
    unsigned short* __restrict__ S2, int N)
{
    __shared__ unsigned short sA[128 * LDA]; // A tile, then H1
    __shared__ unsigned short sB[128 * LDA]; // W1^T, then W2^T
    int tid = threadIdx.x;
    int base = blockIdx.x * 128;

    // stage B1 transposed: sB[n][k] = (k<64 ? W1l[k][n] : W1r[k-64][n])
    for (int i = tid; i < 128 * 128; i += 256) {
        int k = i >> 7, n = i & 127; // consecutive tid -> consecutive n (coalesced)
        float wv = (k < 64) ? W1l[k * HID + n] : W1r[(k - 64) * HID + n];
        sB[n * LDA + k] = bfbits(wv);
    }
    // stage A: cols 0..63 = M1 row (bf16), cols 64..127 = bf16(x row)
    for (int i = tid; i < 128 * 64; i += 256) {
        int r = i >> 6, c = i & 63;
        int node = min(base + r, N - 1);
        sA[r * LDA + c] = M1s[node * 64 + c];
        sA[r * LDA + 64 + c] = bfbits(x[node * 64 + c]);
    }
    __syncthreads();

    int w = tid >> 6, lane = tid & 63;
    int m0 = w * 32;
    int mr = lane & 15, q = lane >> 4;
    const f32x4 zero = {0.f, 0.f, 0.f, 0.f};

    f32x4 acc[2][8];
#pragma unroll
    for (int mt = 0; mt < 2; ++mt)
#pragma unroll
        for (int nt = 0; nt < 8; ++nt) acc[mt][nt] = zero;

#pragma unroll
    for (int kt = 0; kt < 4; ++kt) {
        short8 a0 = *reinterpret_cast<const short8*>(&sA[(m0 + mr) * LDA + kt * 32 + q * 8]);
        short8 a1 = *reinterpret_cast<const short8*>(&sA[(m0 + 16 + mr) * LDA + kt * 32 + q * 8]);
#pragma unroll
        for (int nt = 0; nt < 8; ++nt) {
            short8 b = *reinterpret_cast<const short8*>(&sB[(nt * 16 + mr) * LDA + kt * 32 + q * 8]);
            acc[0][nt] = __builtin_amdgcn_mfma_f32_16x16x32_bf16(a0, b, acc[0][nt], 0, 0, 0);
            acc[1][nt] = __builtin_amdgcn_mfma_f32_16x16x32_bf16(a1, b, acc[1][nt], 0, 0, 0);
        }
    }
    __syncthreads(); // all stage-1 LDS reads done

    // H1 = relu(acc + b1) -> sA (bf16); stage B2 transposed -> sB
#pragma unroll
    for (int mt = 0; mt < 2; ++mt)
#pragma unroll
        for (int nt = 0; nt < 8; ++nt)
#pragma unroll
            for (int j = 0; j < 4; ++j) {
                int row = m0 + mt * 16 + q * 4 + j;
                int col = nt * 16 + mr;
                float v = acc[mt][nt][j] + b1[col];
                sA[row * LDA + col] = bfbits(fmaxf(v, 0.f));
            }
    for (int i = tid; i < 128 * 128; i += 256) {
        int c = i >> 7, n = i & 127;
        float wv = (n < 64) ? W2l[c * HID2 + n] : W2r[c * HID2 + (n - 64)];
        sB[n * LDA + c] = bfbits(wv);
    }
    __syncthreads();

    f32x4 acc2[2][8];
#pragma unroll
    for (int mt = 0; mt < 2; ++mt)
#pragma unroll
        for (int nt = 0; nt < 8; ++nt) acc2[mt][nt] = zero;

#pragma unroll
    for (int kt = 0; kt < 4; ++kt) {
        short8 a0 = *reinterpret_cast<const short8*>(&sA[(m0 + mr) * LDA + kt * 32 + q * 8]);
        short8 a1 = *reinterpret_cast<const short8*>(&sA[(m0 + 16 + mr) * LDA + kt * 32 + q * 8]);
#pragma unroll
        for (int nt = 0; nt < 8; ++nt) {
            short8 b = *reinterpret_cast<const short8*>(&sB[(nt * 16 + mr) * LDA + kt * 32 + q * 8]);
            acc2[0][nt] = __builtin_amdgcn_mfma_f32_16x16x32_bf16(a0, b, acc2[0][nt], 0, 0, 0);
            acc2[1][nt] = __builtin_amdgcn_mfma_f32_16x16x32_bf16(a1, b, acc2[1][nt], 0, 0, 0);
        }
    }

    // epilogue: cols 0..63 -> G (bf16), cols 64..127 -> S2 (bf16)
#pragma unroll
    for (int mt = 0; mt < 2; ++mt)
#pragma unroll
        for (int nt = 0; nt < 8; ++nt)
#pragma unroll
            for (int j = 0; j < 4; ++j) {
                int row = m0 + mt * 16 + q * 4 + j;
                int node = base + row;
                if (node >= N) continue;
                int col = nt * 16 + mr;
                float v = acc2[mt][nt][j];
                if (col < 64) G[node * 64 + col] = bfbits(v);
                else          S2[node * 64 + (col - 64)] = bfbits(v);
            }
}

// ---------------- gather-mean of G + FC + sigmoid ----------------
__global__ __launch_bounds__(256) void agg2fc_kernel(
    const unsigned* __restrict__ Gu, const int* __restrict__ row_ptr,
    const int* __restrict__ srcs, const unsigned* __restrict__ S2u,
    const float* __restrict__ b2, const float* __restrict__ Wfc,
    const float* __restrict__ bfc, float* __restrict__ out, int N)
{
    int g = blockIdx.x * 256 + threadIdx.x;
    int node = g >> 6;
    if (node >= N) return;
    int lane = g & 63, hl = lane & 31, half = lane >> 5;
    int s0 = row_ptr[node], s1 = row_ptr[node + 1];
    float a0 = 0.f, a1 = 0.f;
    for (int e = s0; e < s1; e += 8) {
#pragma unroll
        for (int k = 0; k < 4; ++k) {
            int ek = e + half + 2 * k;
            bool valid = ek < s1;
            int src = srcs[valid ? ek : s0];
            unsigned u = Gu[src * 32 + hl];
            if (valid) { a0 += bflo(u); a1 += bfhi(u); }
        }
    }
    a0 += __shfl_xor(a0, 32);
    a1 += __shfl_xor(a1, 32);
    int deg = s1 - s0;
    float scale = deg > 0 ? 1.f / (float)deg : 0.f;
    int c0 = 2 * hl, c1 = 2 * hl + 1;
    unsigned s2 = S2u[node * 32 + hl];
    float v0 = fmaxf(a0 * scale + bflo(s2) + b2[c0], 0.f) * Wfc[c0];
    float v1 = fmaxf(a1 * scale + bfhi(s2) + b2[c1], 0.f) * Wfc[c1];
    float z = v0 + v1;
    for (int off = 16; off >= 1; off >>= 1) z += __shfl_xor(z, off);
    if (lane == 0) out[node] = 1.f / (1.f + __expf(-(z + bfc[0])));
}

// ---------------- launch ----------------
static inline size_t align_up(size_t v, size_t a) { return (v + a - 1) & ~(a - 1); }

extern "C" void kernel_launch(void* const* d_in, const int* in_sizes, int n_in,
                              void* d_out, int out_size, void* d_ws, size_t ws_size,
                              hipStream_t stream) {
    const float* x   = (const float*)d_in[0];
    const int*   ei  = (const int*)d_in[1];
    const float* W1l = (const float*)d_in[2];
    const float* b1  = (const float*)d_in[3];
    const float* W1r = (const float*)d_in[4];
    const float* W2l = (const float*)d_in[5];
    const float* b2  = (const float*)d_in[6];
    const float* W2r = (const float*)d_in[7];
    const float* Wfc = (const float*)d_in[8];
    const float* bfc = (const float*)d_in[9];
    float* out = (float*)d_out;

    const int N = in_sizes[0] / IN_C;   // 100000
    const int E = in_sizes[1] / 2;      // 1600000

    char* ws = (char*)d_ws;
    size_t o = 0;
    int* deg      = (int*)(ws + o); o = align_up(o + (size_t)N * 4, 256);
    int* row_ptr  = (int*)(ws + o); o = align_up(o + (size_t)(N + 1) * 4, 256);
    int* fill_pos = (int*)(ws + o); o = align_up(o + (size_t)N * 4, 256);
    int* bsum     = (int*)(ws + o); o = align_up(o + 512 * 4, 256);
    int* srcs     = (int*)(ws + o); o = align_up(o + (size_t)E * 4, 256);
    unsigned* xbu = (unsigned*)(ws + o);                   // [N*32] bf16 x; G aliases after agg1
    size_t xbu_off = o; o = align_up(o + (size_t)N * 32 * 4, 256);
    unsigned* M1u = (unsigned*)(ws + o); o = align_up(o + (size_t)N * 32 * 4, 256);
    unsigned* S2u = (unsigned*)(ws + o); o = align_up(o + (size_t)N * 32 * 4, 256);
    unsigned* Gu  = (unsigned*)((char*)d_ws + xbu_off);    // alias: xb dead after agg1

    hipMemsetAsync(deg, 0, (size_t)N * 4, stream);

    int eb = (E + 255) / 256;
    int nb256 = (N + 255) / 256;                 // 391
    convert_x_kernel<<<(N * 32 + 255) / 256, 256, 0, stream>>>((const float2*)x, xbu, N * 32);
    hist_kernel<<<eb, 256, 0, stream>>>(ei, deg, E);
    scanA_kernel<<<nb256, 256, 0, stream>>>(deg, bsum, N);
    scanB_kernel<<<1, 512, 0, stream>>>(bsum, nb256);
    scanC_kernel<<<nb256, 256, 0, stream>>>(deg, bsum, row_ptr, fill_pos, N, E);
    fill_kernel<<<eb, 256, 0, stream>>>(ei, fill_pos, srcs, E);

    int gwb = (N * 64 + 255) / 256;              // wave-per-node grids
    agg1_kernel<<<gwb, 256, 0, stream>>>(xbu, row_ptr, srcs, M1u, N);
    dense_kernel<<<(N + 127) / 128, 256, 0, stream>>>(
        (const unsigned short*)M1u, x, W1l, b1, W1r, W2l, W2r,
        (unsigned short*)Gu, (unsigned short*)S2u, N);
    agg2fc_kernel<<<gwb, 256, 0, stream>>>(Gu, row_ptr, srcs, S2u, b2, Wfc, bfc, out, N);
}

// Round 4
// 489.246 us; speedup vs baseline: 2.2051x; 1.0369x over previous
//
#include <hip/hip_runtime.h>
#include <hip/hip_bf16.h>
#include <math.h>

// FraudGNN on MI355X. CSR build via two-level counting sort (block-private
// partition -> per-bucket local CSR; no global atomics, no write-amp), then
// bf16 gather-mean + one fused MFMA dense kernel + fused FC/sigmoid epilogue.

#define IN_C 64
#define HID 128
#define HID2 64
#define LDA 136     // LDS row stride for MFMA tiles
#define NBSHIFT 9   // 512 nodes per bucket
#define BR 512
#define P1B 256     // partition blocks (NBUCK <= 256 required: N <= 131072)

typedef short short8 __attribute__((ext_vector_type(8)));
typedef float f32x4 __attribute__((ext_vector_type(4)));

__device__ inline unsigned short bfbits(float f) {
    __hip_bfloat16 h = __float2bfloat16(f);
    return *reinterpret_cast<unsigned short*>(&h);
}
__device__ inline float bflo(unsigned u) { return __uint_as_float(u << 16); }
__device__ inline float bfhi(unsigned u) { return __uint_as_float(u & 0xffff0000u); }
__device__ inline unsigned bfpack(float a, float b) {
    return ((unsigned)bfbits(b) << 16) | (unsigned)bfbits(a);
}

// ---------------- x -> bf16 packed ----------------
__global__ void convert_x_kernel(const float2* __restrict__ x2,
                                 unsigned* __restrict__ xbu, int n2) {
    int i = blockIdx.x * 256 + threadIdx.x;
    if (i < n2) { float2 v = x2[i]; xbu[i] = bfpack(v.x, v.y); }
}

// ---------------- CSR build: two-level counting sort ----------------
// P1: each block partitions its private edge chunk into NBUCK dst-buckets,
// writing (src,dst) pairs to a block-private region of `part` (write-amp ~1).
__global__ __launch_bounds__(256) void part_kernel(
    const int* __restrict__ ei, int2* __restrict__ part, int* __restrict__ cnt,
    int E, int EPB, int NBUCK)
{
    __shared__ int hist[256];
    __shared__ int lofs[256];
    __shared__ int wred[4];
    int t = threadIdx.x, j = blockIdx.x;
    int lane = t & 63, w = t >> 6;
    int e0 = j * EPB, e1 = min(e0 + EPB, E);
    hist[t] = 0;
    __syncthreads();
    for (int e = e0 + t; e < e1; e += 256)
        atomicAdd(&hist[ei[E + e] >> NBSHIFT], 1);
    __syncthreads();
    // exclusive scan of hist[256] -> lofs
    int v = hist[t];
    int x = v;
    for (int off = 1; off < 64; off <<= 1) {
        int u = __shfl_up(x, off);
        if (lane >= off) x += u;
    }
    if (lane == 63) wred[w] = x;
    if (t < NBUCK) cnt[j * NBUCK + t] = v; // per-block bucket counts
    __syncthreads();
    int add = 0;
    for (int k = 0; k < w; ++k) add += wred[k];
    lofs[t] = x + add - v;
    __syncthreads();
    for (int e = e0 + t; e < e1; e += 256) {
        int s = ei[e], d = ei[E + e];
        int p = atomicAdd(&lofs[d >> NBSHIFT], 1);
        part[e0 + p] = make_int2(s, d);
    }
}

// offs: per-block prefix along buckets + bucket totals + global bucket bases.
__global__ __launch_bounds__(256) void offs_kernel(
    const int* __restrict__ cnt, int* __restrict__ offs,
    int* __restrict__ bucket_base, int* __restrict__ row_ptr,
    int N, int E, int NBUCK)
{
    __shared__ int tot[256];
    __shared__ int wred[4];
    int t = threadIdx.x, lane = t & 63, w = t >> 6;
    // offs[j][b] = prefix of cnt[j][*] along b (thread t = block j)
    int run = 0;
    for (int b = 0; b < NBUCK; ++b) {
        int c = cnt[t * NBUCK + b];
        offs[t * NBUCK + b] = run;
        run += c;
    }
    // bucket totals (coalesced across t)
    int s = 0;
    if (t < NBUCK)
        for (int j = 0; j < P1B; ++j) s += cnt[j * NBUCK + t];
    tot[t] = (t < NBUCK) ? s : 0;
    __syncthreads();
    int v = tot[t];
    int x = v;
    for (int off = 1; off < 64; off <<= 1) {
        int u = __shfl_up(x, off);
        if (lane >= off) x += u;
    }
    if (lane == 63) wred[w] = x;
    __syncthreads();
    int add = 0;
    for (int k = 0; k < w; ++k) add += wred[k];
    if (t < NBUCK) bucket_base[t] = x + add - v; // exclusive
    if (t == 0) { bucket_base[NBUCK] = E; row_ptr[N] = E; }
}

// P2: one block per bucket (512-node range): LDS hist -> local scan ->
// coalesced row_ptr write -> scatter srcs into bucket-contiguous region.
__global__ __launch_bounds__(256) void csr_kernel(
    const int2* __restrict__ part, const int* __restrict__ cnt,
    const int* __restrict__ offs, const int* __restrict__ bucket_base,
    int* __restrict__ row_ptr, int* __restrict__ srcs,
    int N, int EPB, int NBUCK)
{
    __shared__ int ncnt[BR];
    __shared__ int nofs[BR];
    __shared__ int nfill[BR];
    __shared__ int wred[4];
    int b = blockIdx.x;
    int t = threadIdx.x, lane = t & 63, w = t >> 6;
    int node0 = b << NBSHIFT;
    int nn = min(BR, N - node0);
    ncnt[t] = 0; ncnt[t + 256] = 0;
    __syncthreads();
    for (int j = w; j < P1B; j += 4) {
        int base = j * EPB + offs[j * NBUCK + b];
        int len = cnt[j * NBUCK + b];
        for (int i = lane; i < len; i += 64)
            atomicAdd(&ncnt[part[base + i].y - node0], 1);
    }
    __syncthreads();
    // exclusive scan of ncnt[512], 2 elems/thread
    int c0 = ncnt[2 * t], c1 = ncnt[2 * t + 1];
    int v = c0 + c1;
    int x = v;
    for (int off = 1; off < 64; off <<= 1) {
        int u = __shfl_up(x, off);
        if (lane >= off) x += u;
    }
    if (lane == 63) wred[w] = x;
    __syncthreads();
    int add = 0;
    for (int k = 0; k < w; ++k) add += wred[k];
    int exc = x + add - v;
    nofs[2 * t] = exc;          nofs[2 * t + 1] = exc + c0;
    nfill[2 * t] = exc;         nfill[2 * t + 1] = exc + c0;
    __syncthreads();
    int bbase = bucket_base[b];
    for (int i = t; i < nn; i += 256) row_ptr[node0 + i] = bbase + nofs[i];
    for (int j = w; j < P1B; j += 4) {
        int base = j * EPB + offs[j * NBUCK + b];
        int len = cnt[j * NBUCK + b];
        for (int i = lane; i < len; i += 64) {
            int2 p = part[base + i];
            int pos = atomicAdd(&nfill[p.y - node0], 1);
            srcs[bbase + pos] = p.x;
        }
    }
}

// ---------------- gather-mean of xb -> M1 (bf16) ----------------
__global__ __launch_bounds__(256) void agg1_kernel(
    const unsigned* __restrict__ xbu, const int* __restrict__ row_ptr,
    const int* __restrict__ srcs, unsigned* __restrict__ M1u, int N)
{
    int g = blockIdx.x * 256 + threadIdx.x;
    int node = g >> 6;
    if (node >= N) return;
    int lane = g & 63, hl = lane & 31, half = lane >> 5;
    int s0 = row_ptr[node], s1 = row_ptr[node + 1];
    float a0 = 0.f, a1 = 0.f;
    for (int e = s0; e < s1; e += 16) {
#pragma unroll
        for (int k = 0; k < 8; ++k) {
            int ek = e + half + 2 * k;
            bool valid = ek < s1;
            int src = srcs[valid ? ek : s0];
            unsigned u = xbu[src * 32 + hl];
            if (valid) { a0 += bflo(u); a1 += bfhi(u); }
        }
    }
    a0 += __shfl_xor(a0, 32);
    a1 += __shfl_xor(a1, 32);
    int deg = s1 - s0;
    float scale = deg > 0 ? 1.f / (float)deg : 0.f;
    if (half == 0) M1u[node * 32 + hl] = bfpack(a0 * scale, a1 * scale);
}

// ---------------- fused dense: H1 -> G, S2 (MFMA) ----------------
__global__ __launch_bounds__(256) void dense_kernel(
    const unsigned short* __restrict__ M1s, const float* __restrict__ x,
    const float* __restrict__ W1l, const float* __restrict__ b1,
    const float* __restrict__ W1r, const float* __restrict__ W2l,
    const float* __restrict__ W2r, unsigned short* __restrict__ G,
    unsigned short* __restrict__ S2, int N)
{
    __shared__ unsigned short sA[128 * LDA];
    __shared__ unsigned short sB[128 * LDA];
    int tid = threadIdx.x;
    int base = blockIdx.x * 128;

    for (int i = tid; i < 128 * 128; i += 256) {
        int k = i >> 7, n = i & 127;
        float wv = (k < 64) ? W1l[k * HID + n] : W1r[(k - 64) * HID + n];
        sB[n * LDA + k] = bfbits(wv);
    }
    for (int i = tid; i < 128 * 64; i += 256) {
        int r = i >> 6, c = i & 63;
        int node = min(base + r, N - 1);
        sA[r * LDA + c] = M1s[node * 64 + c];
        sA[r * LDA + 64 + c] = bfbits(x[node * 64 + c]);
    }
    __syncthreads();

    int w = tid >> 6, lane = tid & 63;
    int m0 = w * 32;
    int mr = lane & 15, q = lane >> 4;
    const f32x4 zero = {0.f, 0.f, 0.f, 0.f};

    f32x4 acc[2][8];
#pragma unroll
    for (int mt = 0; mt < 2; ++mt)
#pragma unroll
        for (int nt = 0; nt < 8; ++nt) acc[mt][nt] = zero;

#pragma unroll
    for (int kt = 0; kt < 4; ++kt) {
        short8 a0 = *reinterpret_cast<const short8*>(&sA[(m0 + mr) * LDA + kt * 32 + q * 8]);
        short8 a1 = *reinterpret_cast<const short8*>(&sA[(m0 + 16 + mr) * LDA + kt * 32 + q * 8]);
#pragma unroll
        for (int nt = 0; nt < 8; ++nt) {
            short8 b = *reinterpret_cast<const short8*>(&sB[(nt * 16 + mr) * LDA + kt * 32 + q * 8]);
            acc[0][nt] = __builtin_amdgcn_mfma_f32_16x16x32_bf16(a0, b, acc[0][nt], 0, 0, 0);
            acc[1][nt] = __builtin_amdgcn_mfma_f32_16x16x32_bf16(a1, b, acc[1][nt], 0, 0, 0);
        }
    }
    __syncthreads();

#pragma unroll
    for (int mt = 0; mt < 2; ++mt)
#pragma unroll
        for (int nt = 0; nt < 8; ++nt)
#pragma unroll
            for (int j = 0; j < 4; ++j) {
                int row = m0 + mt * 16 + q * 4 + j;
                int col = nt * 16 + mr;
                float v = acc[mt][nt][j] + b1[col];
                sA[row * LDA + col] = bfbits(fmaxf(v, 0.f));
            }
    for (int i = tid; i < 128 * 128; i += 256) {
        int c = i >> 7, n = i & 127;
        float wv = (n < 64) ? W2l[c * HID2 + n] : W2r[c * HID2 + (n - 64)];
        sB[n * LDA + c] = bfbits(wv);
    }
    __syncthreads();

    f32x4 acc2[2][8];
#pragma unroll
    for (int mt = 0; mt < 2; ++mt)
#pragma unroll
        for (int nt = 0; nt < 8; ++nt) acc2[mt][nt] = zero;

#pragma unroll
    for (int kt = 0; kt < 4; ++kt) {
        short8 a0 = *reinterpret_cast<const short8*>(&sA[(m0 + mr) * LDA + kt * 32 + q * 8]);
        short8 a1 = *reinterpret_cast<const short8*>(&sA[(m0 + 16 + mr) * LDA + kt * 32 + q * 8]);
#pragma unroll
        for (int nt = 0; nt < 8; ++nt) {
            short8 b = *reinterpret_cast<const short8*>(&sB[(nt * 16 + mr) * LDA + kt * 32 + q * 8]);
            acc2[0][nt] = __builtin_amdgcn_mfma_f32_16x16x32_bf16(a0, b, acc2[0][nt], 0, 0, 0);
            acc2[1][nt] = __builtin_amdgcn_mfma_f32_16x16x32_bf16(a1, b, acc2[1][nt], 0, 0, 0);
        }
    }

#pragma unroll
    for (int mt = 0; mt < 2; ++mt)
#pragma unroll
        for (int nt = 0; nt < 8; ++nt)
#pragma unroll
            for (int j = 0; j < 4; ++j) {
                int row = m0 + mt * 16 + q * 4 + j;
                int node = base + row;
                if (node >= N) continue;
                int col = nt * 16 + mr;
                float v = acc2[mt][nt][j];
                if (col < 64) G[node * 64 + col] = bfbits(v);
                else          S2[node * 64 + (col - 64)] = bfbits(v);
            }
}

// ---------------- gather-mean of G + FC + sigmoid ----------------
__global__ __launch_bounds__(256) void agg2fc_kernel(
    const unsigned* __restrict__ Gu, const int* __restrict__ row_ptr,
    const int* __restrict__ srcs, const unsigned* __restrict__ S2u,
    const float* __restrict__ b2, const float* __restrict__ Wfc,
    const float* __restrict__ bfc, float* __restrict__ out, int N)
{
    int g = blockIdx.x * 256 + threadIdx.x;
    int node = g >> 6;
    if (node >= N) return;
    int lane = g & 63, hl = lane & 31, half = lane >> 5;
    int s0 = row_ptr[node], s1 = row_ptr[node + 1];
    float a0 = 0.f, a1 = 0.f;
    for (int e = s0; e < s1; e += 16) {
#pragma unroll
        for (int k = 0; k < 8; ++k) {
            int ek = e + half + 2 * k;
            bool valid = ek < s1;
            int src = srcs[valid ? ek : s0];
            unsigned u = Gu[src * 32 + hl];
            if (valid) { a0 += bflo(u); a1 += bfhi(u); }
        }
    }
    a0 += __shfl_xor(a0, 32);
    a1 += __shfl_xor(a1, 32);
    int deg = s1 - s0;
    float scale = deg > 0 ? 1.f / (float)deg : 0.f;
    int c0 = 2 * hl, c1 = 2 * hl + 1;
    unsigned s2 = S2u[node * 32 + hl];
    float v0 = fmaxf(a0 * scale + bflo(s2) + b2[c0], 0.f) * Wfc[c0];
    float v1 = fmaxf(a1 * scale + bfhi(s2) + b2[c1], 0.f) * Wfc[c1];
    float z = v0 + v1;
    for (int off = 16; off >= 1; off >>= 1) z += __shfl_xor(z, off);
    if (lane == 0) out[node] = 1.f / (1.f + __expf(-(z + bfc[0])));
}

// ---------------- launch ----------------
static inline size_t align_up(size_t v, size_t a) { return (v + a - 1) & ~(a - 1); }

extern "C" void kernel_launch(void* const* d_in, const int* in_sizes, int n_in,
                              void* d_out, int out_size, void* d_ws, size_t ws_size,
                              hipStream_t stream) {
    const float* x   = (const float*)d_in[0];
    const int*   ei  = (const int*)d_in[1];
    const float* W1l = (const float*)d_in[2];
    const float* b1  = (const float*)d_in[3];
    const float* W1r = (const float*)d_in[4];
    const float* W2l = (const float*)d_in[5];
    const float* b2  = (const float*)d_in[6];
    const float* W2r = (const float*)d_in[7];
    const float* Wfc = (const float*)d_in[8];
    const float* bfc = (const float*)d_in[9];
    float* out = (float*)d_out;

    const int N = in_sizes[0] / IN_C;   // 100000
    const int E = in_sizes[1] / 2;      // 1600000
    const int NBUCK = (N + BR - 1) / BR;        // 196 (<=256)
    const int EPB = (E + P1B - 1) / P1B;        // 6250

    char* ws = (char*)d_ws;
    size_t o = 0;
    int* row_ptr  = (int*)(ws + o); o = align_up(o + (size_t)(N + 1) * 4, 256);
    int* srcs     = (int*)(ws + o); o = align_up(o + (size_t)E * 4, 256);
    int* cnt      = (int*)(ws + o); o = align_up(o + (size_t)P1B * 256 * 4, 256);
    int* offs     = (int*)(ws + o); o = align_up(o + (size_t)P1B * 256 * 4, 256);
    int* bb       = (int*)(ws + o); o = align_up(o + 257 * 4, 256);
    // part aliases S2u (part dead before dense writes S2); xbu aliases Gu.
    size_t part_off = o; o = align_up(o + (size_t)E * 8 > (size_t)N * 128 ?
                                      o + (size_t)E * 8 : o + (size_t)N * 128, 256);
    int2* part = (int2*)(ws + part_off);
    unsigned* S2u = (unsigned*)(ws + part_off);
    size_t xbu_off = o; o = align_up(o + (size_t)N * 32 * 4, 256);
    unsigned* xbu = (unsigned*)(ws + xbu_off);
    unsigned* Gu  = (unsigned*)(ws + xbu_off);
    unsigned* M1u = (unsigned*)(ws + o); o = align_up(o + (size_t)N * 32 * 4, 256);

    convert_x_kernel<<<(N * 32 + 255) / 256, 256, 0, stream>>>((const float2*)x, xbu, N * 32);
    part_kernel<<<P1B, 256, 0, stream>>>(ei, part, cnt, E, EPB, NBUCK);
    offs_kernel<<<1, 256, 0, stream>>>(cnt, offs, bb, row_ptr, N, E, NBUCK);
    csr_kernel<<<NBUCK, 256, 0, stream>>>(part, cnt, offs, bb, row_ptr, srcs, N, EPB, NBUCK);

    int gwb = (N * 64 + 255) / 256;
    agg1_kernel<<<gwb, 256, 0, stream>>>(xbu, row_ptr, srcs, M1u, N);
    dense_kernel<<<(N + 127) / 128, 256, 0, stream>>>(
        (const unsigned short*)M1u, x, W1l, b1, W1r, W2l, W2r,
        (unsigned short*)Gu, (unsigned short*)S2u, N);
    agg2fc_kernel<<<gwb, 256, 0, stream>>>(Gu, row_ptr, srcs, S2u, b2, Wfc, bfc, out, N);
}

// Round 5
// 459.324 us; speedup vs baseline: 2.3487x; 1.0651x over previous
//
#include <hip/hip_runtime.h>
#include <hip/hip_bf16.h>
#include <math.h>

// FraudGNN on MI355X. CSR build via two-level counting sort, bf16 gather for
// layer 1, fp8(e4m3) gather for layer 2 (table fits per-XCD L2), fused MFMA
// dense kernel with LDS-staged coalesced epilogue.

#define IN_C 64
#define HID 128
#define HID2 64
#define LDA 136     // LDS row stride for MFMA tiles
#define NBSHIFT 9   // 512 nodes per bucket
#define BR 512
#define P1B 256     // partition blocks (needs NBUCK <= 256: N <= 131072)

typedef short short8 __attribute__((ext_vector_type(8)));
typedef float f32x4 __attribute__((ext_vector_type(4)));
typedef float f32x2 __attribute__((ext_vector_type(2)));

__device__ inline unsigned short bfbits(float f) {
    __hip_bfloat16 h = __float2bfloat16(f);
    return *reinterpret_cast<unsigned short*>(&h);
}
__device__ inline float bflo(unsigned u) { return __uint_as_float(u << 16); }
__device__ inline float bfhi(unsigned u) { return __uint_as_float(u & 0xffff0000u); }
__device__ inline unsigned bfpack(float a, float b) {
    return ((unsigned)bfbits(b) << 16) | (unsigned)bfbits(a);
}
__device__ inline unsigned char f_to_fp8(float v) {
    return (unsigned char)(__builtin_amdgcn_cvt_pk_fp8_f32(v, v, 0, false) & 0xff);
}

// ---------------- CSR build: two-level counting sort ----------------
// P1: block-private dst-bucket partition (write-amp ~1); also converts x->bf16
// grid-stride (folded convert kernel).
__global__ __launch_bounds__(256) void part_kernel(
    const int* __restrict__ ei, int2* __restrict__ part, int* __restrict__ cnt,
    const float2* __restrict__ x2, unsigned* __restrict__ xbu, int n2,
    int E, int EPB, int NBUCK)
{
    __shared__ int hist[256];
    __shared__ int lofs[256];
    __shared__ int wred[4];
    int t = threadIdx.x, j = blockIdx.x;
    int lane = t & 63, w = t >> 6;
    int e0 = j * EPB, e1 = min(e0 + EPB, E);
    hist[t] = 0;
    __syncthreads();
    for (int e = e0 + t; e < e1; e += 256)
        atomicAdd(&hist[ei[E + e] >> NBSHIFT], 1);
    // folded x -> bf16 conversion (independent of hist)
    for (int i = j * 256 + t; i < n2; i += P1B * 256) {
        float2 v = x2[i];
        xbu[i] = bfpack(v.x, v.y);
    }
    __syncthreads();
    int v = hist[t];
    int x = v;
    for (int off = 1; off < 64; off <<= 1) {
        int u = __shfl_up(x, off);
        if (lane >= off) x += u;
    }
    if (lane == 63) wred[w] = x;
    if (t < NBUCK) cnt[j * NBUCK + t] = v;
    __syncthreads();
    int add = 0;
    for (int k = 0; k < w; ++k) add += wred[k];
    lofs[t] = x + add - v;
    __syncthreads();
    for (int e = e0 + t; e < e1; e += 256) {
        int s = ei[e], d = ei[E + e];
        int p = atomicAdd(&lofs[d >> NBSHIFT], 1);
        part[e0 + p] = make_int2(s, d);
    }
}

__global__ __launch_bounds__(256) void offs_kernel(
    const int* __restrict__ cnt, int* __restrict__ offs,
    int* __restrict__ bucket_base, int* __restrict__ row_ptr,
    int N, int E, int NBUCK)
{
    __shared__ int tot[256];
    __shared__ int wred[4];
    int t = threadIdx.x, lane = t & 63, w = t >> 6;
    int run = 0;
    for (int b = 0; b < NBUCK; ++b) {
        int c = cnt[t * NBUCK + b];
        offs[t * NBUCK + b] = run;
        run += c;
    }
    int s = 0;
    if (t < NBUCK)
        for (int j = 0; j < P1B; ++j) s += cnt[j * NBUCK + t];
    tot[t] = (t < NBUCK) ? s : 0;
    __syncthreads();
    int v = tot[t];
    int x = v;
    for (int off = 1; off < 64; off <<= 1) {
        int u = __shfl_up(x, off);
        if (lane >= off) x += u;
    }
    if (lane == 63) wred[w] = x;
    __syncthreads();
    int add = 0;
    for (int k = 0; k < w; ++k) add += wred[k];
    if (t < NBUCK) bucket_base[t] = x + add - v;
    if (t == 0) { bucket_base[NBUCK] = E; row_ptr[N] = E; }
}

__global__ __launch_bounds__(256) void csr_kernel(
    const int2* __restrict__ part, const int* __restrict__ cnt,
    const int* __restrict__ offs, const int* __restrict__ bucket_base,
    int* __restrict__ row_ptr, int* __restrict__ srcs,
    int N, int EPB, int NBUCK)
{
    __shared__ int ncnt[BR];
    __shared__ int nofs[BR];
    __shared__ int nfill[BR];
    __shared__ int wred[4];
    int b = blockIdx.x;
    int t = threadIdx.x, lane = t & 63, w = t >> 6;
    int node0 = b << NBSHIFT;
    int nn = min(BR, N - node0);
    ncnt[t] = 0; ncnt[t + 256] = 0;
    __syncthreads();
    for (int j = w; j < P1B; j += 4) {
        int base = j * EPB + offs[j * NBUCK + b];
        int len = cnt[j * NBUCK + b];
        for (int i = lane; i < len; i += 64)
            atomicAdd(&ncnt[part[base + i].y - node0], 1);
    }
    __syncthreads();
    int c0 = ncnt[2 * t], c1 = ncnt[2 * t + 1];
    int v = c0 + c1;
    int x = v;
    for (int off = 1; off < 64; off <<= 1) {
        int u = __shfl_up(x, off);
        if (lane >= off) x += u;
    }
    if (lane == 63) wred[w] = x;
    __syncthreads();
    int add = 0;
    for (int k = 0; k < w; ++k) add += wred[k];
    int exc = x + add - v;
    nofs[2 * t] = exc;          nofs[2 * t + 1] = exc + c0;
    nfill[2 * t] = exc;         nfill[2 * t + 1] = exc + c0;
    __syncthreads();
    int bbase = bucket_base[b];
    for (int i = t; i < nn; i += 256) row_ptr[node0 + i] = bbase + nofs[i];
    for (int j = w; j < P1B; j += 4) {
        int base = j * EPB + offs[j * NBUCK + b];
        int len = cnt[j * NBUCK + b];
        for (int i = lane; i < len; i += 64) {
            int2 p = part[base + i];
            int pos = atomicAdd(&nfill[p.y - node0], 1);
            srcs[bbase + pos] = p.x;
        }
    }
}

// ---------------- gather-mean of xb -> M1 (bf16) ----------------
__global__ __launch_bounds__(256) void agg1_kernel(
    const unsigned* __restrict__ xbu, const int* __restrict__ row_ptr,
    const int* __restrict__ srcs, unsigned* __restrict__ M1u, int N)
{
    int g = blockIdx.x * 256 + threadIdx.x;
    int node = g >> 6;
    if (node >= N) return;
    int lane = g & 63, hl = lane & 31, half = lane >> 5;
    int s0 = row_ptr[node], s1 = row_ptr[node + 1];
    float a0 = 0.f, a1 = 0.f;
    for (int e = s0; e < s1; e += 16) {
#pragma unroll
        for (int k = 0; k < 8; ++k) {
            int ek = e + half + 2 * k;
            bool valid = ek < s1;
            int src = srcs[valid ? ek : 0];
            unsigned u = xbu[src * 32 + hl];
            if (valid) { a0 += bflo(u); a1 += bfhi(u); }
        }
    }
    a0 += __shfl_xor(a0, 32);
    a1 += __shfl_xor(a1, 32);
    int deg = s1 - s0;
    float scale = deg > 0 ? 1.f / (float)deg : 0.f;
    if (half == 0) M1u[node * 32 + hl] = bfpack(a0 * scale, a1 * scale);
}

// ---------------- fused dense: H1 -> G (fp8), S2 (bf16) ----------------
__global__ __launch_bounds__(256) void dense_kernel(
    const unsigned short* __restrict__ M1s, const unsigned short* __restrict__ xbs,
    const float* __restrict__ W1l, const float* __restrict__ b1,
    const float* __restrict__ W1r, const float* __restrict__ W2l,
    const float* __restrict__ W2r, unsigned* __restrict__ G8,
    unsigned* __restrict__ S2u, int N)
{
    __shared__ unsigned short sA[128 * LDA];
    __shared__ unsigned short sB[128 * LDA];
    int tid = threadIdx.x;
    int base = blockIdx.x * 128;

    for (int i = tid; i < 128 * 128; i += 256) {
        int k = i >> 7, n = i & 127;
        float wv = (k < 64) ? W1l[k * HID + n] : W1r[(k - 64) * HID + n];
        sB[n * LDA + k] = bfbits(wv);
    }
    for (int i = tid; i < 128 * 64; i += 256) {
        int r = i >> 6, c = i & 63;
        int node = min(base + r, N - 1);
        sA[r * LDA + c] = M1s[node * 64 + c];
        sA[r * LDA + 64 + c] = xbs[node * 64 + c];
    }
    __syncthreads();

    int w = tid >> 6, lane = tid & 63;
    int m0 = w * 32;
    int mr = lane & 15, q = lane >> 4;
    const f32x4 zero = {0.f, 0.f, 0.f, 0.f};

    f32x4 acc[2][8];
#pragma unroll
    for (int mt = 0; mt < 2; ++mt)
#pragma unroll
        for (int nt = 0; nt < 8; ++nt) acc[mt][nt] = zero;

#pragma unroll
    for (int kt = 0; kt < 4; ++kt) {
        short8 a0 = *reinterpret_cast<const short8*>(&sA[(m0 + mr) * LDA + kt * 32 + q * 8]);
        short8 a1 = *reinterpret_cast<const short8*>(&sA[(m0 + 16 + mr) * LDA + kt * 32 + q * 8]);
#pragma unroll
        for (int nt = 0; nt < 8; ++nt) {
            short8 b = *reinterpret_cast<const short8*>(&sB[(nt * 16 + mr) * LDA + kt * 32 + q * 8]);
            acc[0][nt] = __builtin_amdgcn_mfma_f32_16x16x32_bf16(a0, b, acc[0][nt], 0, 0, 0);
            acc[1][nt] = __builtin_amdgcn_mfma_f32_16x16x32_bf16(a1, b, acc[1][nt], 0, 0, 0);
        }
    }
    __syncthreads();

#pragma unroll
    for (int mt = 0; mt < 2; ++mt)
#pragma unroll
        for (int nt = 0; nt < 8; ++nt)
#pragma unroll
            for (int j = 0; j < 4; ++j) {
                int row = m0 + mt * 16 + q * 4 + j;
                int col = nt * 16 + mr;
                float v = acc[mt][nt][j] + b1[col];
                sA[row * LDA + col] = bfbits(fmaxf(v, 0.f));
            }
    for (int i = tid; i < 128 * 128; i += 256) {
        int c = i >> 7, n = i & 127;
        float wv = (n < 64) ? W2l[c * HID2 + n] : W2r[c * HID2 + (n - 64)];
        sB[n * LDA + c] = bfbits(wv);
    }
    __syncthreads();

    f32x4 acc2[2][8];
#pragma unroll
    for (int mt = 0; mt < 2; ++mt)
#pragma unroll
        for (int nt = 0; nt < 8; ++nt) acc2[mt][nt] = zero;

#pragma unroll
    for (int kt = 0; kt < 4; ++kt) {
        short8 a0 = *reinterpret_cast<const short8*>(&sA[(m0 + mr) * LDA + kt * 32 + q * 8]);
        short8 a1 = *reinterpret_cast<const short8*>(&sA[(m0 + 16 + mr) * LDA + kt * 32 + q * 8]);
#pragma unroll
        for (int nt = 0; nt < 8; ++nt) {
            short8 b = *reinterpret_cast<const short8*>(&sB[(nt * 16 + mr) * LDA + kt * 32 + q * 8]);
            acc2[0][nt] = __builtin_amdgcn_mfma_f32_16x16x32_bf16(a0, b, acc2[0][nt], 0, 0, 0);
            acc2[1][nt] = __builtin_amdgcn_mfma_f32_16x16x32_bf16(a1, b, acc2[1][nt], 0, 0, 0);
        }
    }
    __syncthreads(); // stage-2 LDS reads done; reuse sA/sB as output staging

    unsigned char* sG = (unsigned char*)sA;     // [128][64] fp8
    unsigned short* sS = (unsigned short*)sB;   // [128][64] bf16
#pragma unroll
    for (int mt = 0; mt < 2; ++mt)
#pragma unroll
        for (int nt = 0; nt < 8; ++nt)
#pragma unroll
            for (int j = 0; j < 4; ++j) {
                int row = m0 + mt * 16 + q * 4 + j;
                int col = nt * 16 + mr;
                float v = acc2[mt][nt][j];
                if (col < 64) sG[row * 64 + col] = f_to_fp8(v);
                else          sS[row * 64 + (col - 64)] = bfbits(v);
            }
    __syncthreads();
    const unsigned* sGu = (const unsigned*)sG;
    for (int i = tid; i < 128 * 16; i += 256) {
        int r = i >> 4, node = base + r;
        if (node < N) G8[node * 16 + (i & 15)] = sGu[i];
    }
    const unsigned* sSu = (const unsigned*)sS;
    for (int i = tid; i < 128 * 32; i += 256) {
        int r = i >> 5, node = base + r;
        if (node < N) S2u[node * 32 + (i & 31)] = sSu[i];
    }
}

// ---------------- gather-mean of G(fp8) + FC + sigmoid ----------------
// Quarter-wave (16 lanes x 4B = 64B = 1 line) per edge; 4 edges per load inst.
__global__ __launch_bounds__(256) void agg2fc_kernel(
    const unsigned* __restrict__ G8, const int* __restrict__ row_ptr,
    const int* __restrict__ srcs, const unsigned* __restrict__ S2u,
    const float* __restrict__ b2, const float* __restrict__ Wfc,
    const float* __restrict__ bfc, float* __restrict__ out, int N)
{
    int g = blockIdx.x * 256 + threadIdx.x;
    int node = g >> 6;
    if (node >= N) return;
    int lane = g & 63, ql = lane & 15, quarter = lane >> 4;
    int s0 = row_ptr[node], s1 = row_ptr[node + 1];
    float a0 = 0.f, a1 = 0.f, a2 = 0.f, a3 = 0.f;
    for (int e = s0; e < s1; e += 16) {
#pragma unroll
        for (int k = 0; k < 4; ++k) {
            int ek = e + quarter + 4 * k;
            bool valid = ek < s1;
            int src = srcs[valid ? ek : 0];
            unsigned u = G8[src * 16 + ql];
            if (valid) {
                f32x2 lo = __builtin_amdgcn_cvt_pk_f32_fp8((int)u, false);
                f32x2 hi = __builtin_amdgcn_cvt_pk_f32_fp8((int)u, true);
                a0 += lo[0]; a1 += lo[1]; a2 += hi[0]; a3 += hi[1];
            }
        }
    }
    a0 += __shfl_xor(a0, 16); a0 += __shfl_xor(a0, 32);
    a1 += __shfl_xor(a1, 16); a1 += __shfl_xor(a1, 32);
    a2 += __shfl_xor(a2, 16); a2 += __shfl_xor(a2, 32);
    a3 += __shfl_xor(a3, 16); a3 += __shfl_xor(a3, 32);
    int deg = s1 - s0;
    float scale = deg > 0 ? 1.f / (float)deg : 0.f;
    uint2 s2p = ((const uint2*)(S2u + (size_t)node * 32))[ql];
    float4 b4 = ((const float4*)b2)[ql];
    float4 w4 = ((const float4*)Wfc)[ql];
    float z = fmaxf(a0 * scale + bflo(s2p.x) + b4.x, 0.f) * w4.x
            + fmaxf(a1 * scale + bfhi(s2p.x) + b4.y, 0.f) * w4.y
            + fmaxf(a2 * scale + bflo(s2p.y) + b4.z, 0.f) * w4.z
            + fmaxf(a3 * scale + bfhi(s2p.y) + b4.w, 0.f) * w4.w;
    z += __shfl_xor(z, 1); z += __shfl_xor(z, 2);
    z += __shfl_xor(z, 4); z += __shfl_xor(z, 8);
    if (lane == 0) out[node] = 1.f / (1.f + __expf(-(z + bfc[0])));
}

// ---------------- launch ----------------
static inline size_t align_up(size_t v, size_t a) { return (v + a - 1) & ~(a - 1); }

extern "C" void kernel_launch(void* const* d_in, const int* in_sizes, int n_in,
                              void* d_out, int out_size, void* d_ws, size_t ws_size,
                              hipStream_t stream) {
    const float* x   = (const float*)d_in[0];
    const int*   ei  = (const int*)d_in[1];
    const float* W1l = (const float*)d_in[2];
    const float* b1  = (const float*)d_in[3];
    const float* W1r = (const float*)d_in[4];
    const float* W2l = (const float*)d_in[5];
    const float* b2  = (const float*)d_in[6];
    const float* W2r = (const float*)d_in[7];
    const float* Wfc = (const float*)d_in[8];
    const float* bfc = (const float*)d_in[9];
    float* out = (float*)d_out;

    const int N = in_sizes[0] / IN_C;   // 100000
    const int E = in_sizes[1] / 2;      // 1600000
    const int NBUCK = (N + BR - 1) / BR;        // 196
    const int EPB = (E + P1B - 1) / P1B;        // 6250

    char* ws = (char*)d_ws;
    size_t o = 0;
    int* row_ptr  = (int*)(ws + o); o = align_up(o + (size_t)(N + 1) * 4, 256);
    int* srcs     = (int*)(ws + o); o = align_up(o + (size_t)E * 4, 256);
    int* cnt      = (int*)(ws + o); o = align_up(o + (size_t)P1B * 256 * 4, 256);
    int* offs     = (int*)(ws + o); o = align_up(o + (size_t)P1B * 256 * 4, 256);
    int* bb       = (int*)(ws + o); o = align_up(o + 257 * 4, 256);
    // part (E*8 = 12.8 MB) aliases S2u (N*128 B = 12.8 MB): part dead after csr.
    size_t part_off = o;
    size_t sz1 = (size_t)E * 8, sz2 = (size_t)N * 128;
    o = align_up(part_off + (sz1 > sz2 ? sz1 : sz2), 256);
    int2* part = (int2*)(ws + part_off);
    unsigned* S2u = (unsigned*)(ws + part_off);
    unsigned* xbu = (unsigned*)(ws + o); o = align_up(o + (size_t)N * 32 * 4, 256);
    unsigned* M1u = (unsigned*)(ws + o); o = align_up(o + (size_t)N * 32 * 4, 256);
    unsigned* G8  = (unsigned*)(ws + o); o = align_up(o + (size_t)N * 16 * 4, 256);

    part_kernel<<<P1B, 256, 0, stream>>>(ei, part, cnt, (const float2*)x, xbu,
                                         N * 32, E, EPB, NBUCK);
    offs_kernel<<<1, 256, 0, stream>>>(cnt, offs, bb, row_ptr, N, E, NBUCK);
    csr_kernel<<<NBUCK, 256, 0, stream>>>(part, cnt, offs, bb, row_ptr, srcs, N, EPB, NBUCK);

    int gwb = (N * 64 + 255) / 256;
    agg1_kernel<<<gwb, 256, 0, stream>>>(xbu, row_ptr, srcs, M1u, N);
    dense_kernel<<<(N + 127) / 128, 256, 0, stream>>>(
        (const unsigned short*)M1u, (const unsigned short*)xbu,
        W1l, b1, W1r, W2l, W2r, G8, S2u, N);
    agg2fc_kernel<<<gwb, 256, 0, stream>>>(G8, row_ptr, srcs, S2u, b2, Wfc, bfc, out, N);
}

// Round 6
// 327.474 us; speedup vs baseline: 3.2944x; 1.4026x over previous
//
#include <hip/hip_runtime.h>
#include <hip/hip_bf16.h>
#include <math.h>

// FraudGNN on MI355X. Counting-sort CSR with globally bucket-contiguous
// partition (coalesced csr build), fp8 gathers for BOTH layers (tables fit
// per-XCD L2), fused MFMA dense kernel, fused FC/sigmoid epilogue.

#define IN_C 64
#define HID 128
#define HID2 64
#define LDA 136     // LDS row stride for MFMA tiles
#define NBSHIFT 9   // 512 nodes per bucket
#define BR 512
#define P1B 256     // partition blocks (needs NBUCK <= 256: N <= 131072)

typedef short short8 __attribute__((ext_vector_type(8)));
typedef float f32x4 __attribute__((ext_vector_type(4)));
typedef float f32x2 __attribute__((ext_vector_type(2)));

__device__ inline unsigned short bfbits(float f) {
    __hip_bfloat16 h = __float2bfloat16(f);
    return *reinterpret_cast<unsigned short*>(&h);
}
__device__ inline float bflo(unsigned u) { return __uint_as_float(u << 16); }
__device__ inline float bfhi(unsigned u) { return __uint_as_float(u & 0xffff0000u); }
__device__ inline unsigned bfpack(float a, float b) {
    return ((unsigned)bfbits(b) << 16) | (unsigned)bfbits(a);
}
__device__ inline unsigned char f_to_fp8(float v) {
    return (unsigned char)(__builtin_amdgcn_cvt_pk_fp8_f32(v, v, 0, false) & 0xff);
}

// ---------------- CSR build: counting sort, bucket-contiguous ----------------
// k1: per-block bucket histogram of dst; folds x -> {bf16, fp8} conversion.
__global__ __launch_bounds__(256) void count_kernel(
    const int* __restrict__ ei, int* __restrict__ cnt,
    const float4* __restrict__ x4, unsigned* __restrict__ xbu,
    unsigned* __restrict__ xf8, int n4, int E, int EPB, int NBUCK)
{
    __shared__ int hist[256];
    int t = threadIdx.x, j = blockIdx.x;
    hist[t] = 0;
    __syncthreads();
    int e0 = j * EPB, e1 = min(e0 + EPB, E);
    for (int e = e0 + t; e < e1; e += 256)
        atomicAdd(&hist[ei[E + e] >> NBSHIFT], 1);
    // folded x conversion (independent work, hides hist latency)
    for (int i = j * 256 + t; i < n4; i += P1B * 256) {
        float4 f = x4[i];
        xbu[2 * i]     = bfpack(f.x, f.y);
        xbu[2 * i + 1] = bfpack(f.z, f.w);
        int lo = __builtin_amdgcn_cvt_pk_fp8_f32(f.x, f.y, 0, false);
        xf8[i] = (unsigned)__builtin_amdgcn_cvt_pk_fp8_f32(f.z, f.w, lo, true);
    }
    __syncthreads();
    if (t < NBUCK) cnt[j * NBUCK + t] = hist[t];
}

// k2: bucket totals -> bucket_base; global scatter bases gofs[j][b].
__global__ __launch_bounds__(256) void offs_kernel(
    const int* __restrict__ cnt, int* __restrict__ gofs,
    int* __restrict__ bucket_base, int* __restrict__ row_ptr,
    int N, int E, int NBUCK)
{
    __shared__ int tot[256];
    __shared__ int wred[4];
    int t = threadIdx.x, lane = t & 63, w = t >> 6;
    int run = 0;
    for (int j = 0; j < P1B; ++j)
        run += (t < NBUCK) ? cnt[j * NBUCK + t] : 0;  // coalesced per j
    tot[t] = run;
    __syncthreads();
    int v = tot[t];
    int x = v;
    for (int off = 1; off < 64; off <<= 1) {
        int u = __shfl_up(x, off);
        if (lane >= off) x += u;
    }
    if (lane == 63) wred[w] = x;
    __syncthreads();
    int add = 0;
    for (int k = 0; k < w; ++k) add += wred[k];
    int bb = x + add - v;                  // exclusive bucket base
    if (t < NBUCK) bucket_base[t] = bb;
    if (t == 0) { bucket_base[NBUCK] = E; row_ptr[N] = E; }
    int run2 = bb;
    for (int j = 0; j < P1B; ++j) {
        if (t < NBUCK) {
            gofs[j * NBUCK + t] = run2;    // coalesced per j
            run2 += cnt[j * NBUCK + t];
        }
    }
}

// k3: scatter (src,dst) into globally bucket-contiguous part[].
__global__ __launch_bounds__(256) void scatter_kernel(
    const int* __restrict__ ei, const int* __restrict__ gofs,
    int2* __restrict__ part, int E, int EPB, int NBUCK)
{
    __shared__ int lofs[256];
    int t = threadIdx.x, j = blockIdx.x;
    lofs[t] = (t < NBUCK) ? gofs[j * NBUCK + t] : 0;
    __syncthreads();
    int e0 = j * EPB, e1 = min(e0 + EPB, E);
    for (int e = e0 + t; e < e1; e += 256) {
        int s = ei[e], d = ei[E + e];
        int p = atomicAdd(&lofs[d >> NBSHIFT], 1);
        part[p] = make_int2(s, d);
    }
}

// k4: per-bucket CSR: two coalesced streaming passes over part[gb0,gb1).
__global__ __launch_bounds__(256) void csr_kernel(
    const int2* __restrict__ part, const int* __restrict__ bucket_base,
    int* __restrict__ row_ptr, int* __restrict__ srcs, int N)
{
    __shared__ int ncnt[BR];
    __shared__ int nofs[BR];
    __shared__ int nfill[BR];
    __shared__ int wred[4];
    int b = blockIdx.x;
    int t = threadIdx.x, lane = t & 63, w = t >> 6;
    int node0 = b << NBSHIFT;
    int nn = min(BR, N - node0);
    int gb0 = bucket_base[b], gb1 = bucket_base[b + 1];
    ncnt[t] = 0; ncnt[t + 256] = 0;
    __syncthreads();
    for (int i = gb0 + t; i < gb1; i += 256)
        atomicAdd(&ncnt[part[i].y - node0], 1);
    __syncthreads();
    int c0 = ncnt[2 * t], c1 = ncnt[2 * t + 1];
    int v = c0 + c1;
    int x = v;
    for (int off = 1; off < 64; off <<= 1) {
        int u = __shfl_up(x, off);
        if (lane >= off) x += u;
    }
    if (lane == 63) wred[w] = x;
    __syncthreads();
    int add = 0;
    for (int k = 0; k < w; ++k) add += wred[k];
    int exc = x + add - v;
    nofs[2 * t] = exc;          nofs[2 * t + 1] = exc + c0;
    nfill[2 * t] = exc;         nfill[2 * t + 1] = exc + c0;
    __syncthreads();
    for (int i = t; i < nn; i += 256) row_ptr[node0 + i] = gb0 + nofs[i];
    for (int i = gb0 + t; i < gb1; i += 256) {
        int2 p = part[i];
        int pos = atomicAdd(&nfill[p.y - node0], 1);
        srcs[gb0 + pos] = p.x;
    }
}

// ---------------- gather-mean of x(fp8) -> M1 (bf16) ----------------
// Quarter-wave (16 lanes x 4B = 64B = 1 line) per edge; 4 edges per load inst.
__global__ __launch_bounds__(256) void agg1_kernel(
    const unsigned* __restrict__ xf8, const int* __restrict__ row_ptr,
    const int* __restrict__ srcs, unsigned* __restrict__ M1u, int N)
{
    int g = blockIdx.x * 256 + threadIdx.x;
    int node = g >> 6;
    if (node >= N) return;
    int lane = g & 63, ql = lane & 15, quarter = lane >> 4;
    int s0 = row_ptr[node], s1 = row_ptr[node + 1];
    float a0 = 0.f, a1 = 0.f, a2 = 0.f, a3 = 0.f;
    for (int e = s0; e < s1; e += 16) {
#pragma unroll
        for (int k = 0; k < 4; ++k) {
            int ek = e + quarter + 4 * k;
            bool valid = ek < s1;
            int src = srcs[valid ? ek : 0];
            unsigned u = xf8[src * 16 + ql];
            if (valid) {
                f32x2 lo = __builtin_amdgcn_cvt_pk_f32_fp8((int)u, false);
                f32x2 hi = __builtin_amdgcn_cvt_pk_f32_fp8((int)u, true);
                a0 += lo[0]; a1 += lo[1]; a2 += hi[0]; a3 += hi[1];
            }
        }
    }
    a0 += __shfl_xor(a0, 16); a0 += __shfl_xor(a0, 32);
    a1 += __shfl_xor(a1, 16); a1 += __shfl_xor(a1, 32);
    a2 += __shfl_xor(a2, 16); a2 += __shfl_xor(a2, 32);
    a3 += __shfl_xor(a3, 16); a3 += __shfl_xor(a3, 32);
    int deg = s1 - s0;
    float scale = deg > 0 ? 1.f / (float)deg : 0.f;
    if (quarter == 0) {
        uint2 p;
        p.x = bfpack(a0 * scale, a1 * scale);
        p.y = bfpack(a2 * scale, a3 * scale);
        ((uint2*)M1u)[node * 16 + ql] = p;
    }
}

// ---------------- fused dense: H1 -> G (fp8), S2 (bf16) ----------------
__global__ __launch_bounds__(256) void dense_kernel(
    const unsigned short* __restrict__ M1s, const unsigned short* __restrict__ xbs,
    const float* __restrict__ W1l, const float* __restrict__ b1,
    const float* __restrict__ W1r, const float* __restrict__ W2l,
    const float* __restrict__ W2r, unsigned* __restrict__ G8,
    unsigned* __restrict__ S2u, int N)
{
    __shared__ unsigned short sA[128 * LDA];
    __shared__ unsigned short sB[128 * LDA];
    int tid = threadIdx.x;
    int base = blockIdx.x * 128;

    for (int i = tid; i < 128 * 128; i += 256) {
        int k = i >> 7, n = i & 127;
        float wv = (k < 64) ? W1l[k * HID + n] : W1r[(k - 64) * HID + n];
        sB[n * LDA + k] = bfbits(wv);
    }
    for (int i = tid; i < 128 * 64; i += 256) {
        int r = i >> 6, c = i & 63;
        int node = min(base + r, N - 1);
        sA[r * LDA + c] = M1s[node * 64 + c];
        sA[r * LDA + 64 + c] = xbs[node * 64 + c];
    }
    __syncthreads();

    int w = tid >> 6, lane = tid & 63;
    int m0 = w * 32;
    int mr = lane & 15, q = lane >> 4;
    const f32x4 zero = {0.f, 0.f, 0.f, 0.f};

    f32x4 acc[2][8];
#pragma unroll
    for (int mt = 0; mt < 2; ++mt)
#pragma unroll
        for (int nt = 0; nt < 8; ++nt) acc[mt][nt] = zero;

#pragma unroll
    for (int kt = 0; kt < 4; ++kt) {
        short8 a0 = *reinterpret_cast<const short8*>(&sA[(m0 + mr) * LDA + kt * 32 + q * 8]);
        short8 a1 = *reinterpret_cast<const short8*>(&sA[(m0 + 16 + mr) * LDA + kt * 32 + q * 8]);
#pragma unroll
        for (int nt = 0; nt < 8; ++nt) {
            short8 b = *reinterpret_cast<const short8*>(&sB[(nt * 16 + mr) * LDA + kt * 32 + q * 8]);
            acc[0][nt] = __builtin_amdgcn_mfma_f32_16x16x32_bf16(a0, b, acc[0][nt], 0, 0, 0);
            acc[1][nt] = __builtin_amdgcn_mfma_f32_16x16x32_bf16(a1, b, acc[1][nt], 0, 0, 0);
        }
    }
    __syncthreads();

#pragma unroll
    for (int mt = 0; mt < 2; ++mt)
#pragma unroll
        for (int nt = 0; nt < 8; ++nt)
#pragma unroll
            for (int j = 0; j < 4; ++j) {
                int row = m0 + mt * 16 + q * 4 + j;
                int col = nt * 16 + mr;
                float v = acc[mt][nt][j] + b1[col];
                sA[row * LDA + col] = bfbits(fmaxf(v, 0.f));
            }
    for (int i = tid; i < 128 * 128; i += 256) {
        int c = i >> 7, n = i & 127;
        float wv = (n < 64) ? W2l[c * HID2 + n] : W2r[c * HID2 + (n - 64)];
        sB[n * LDA + c] = bfbits(wv);
    }
    __syncthreads();

    f32x4 acc2[2][8];
#pragma unroll
    for (int mt = 0; mt < 2; ++mt)
#pragma unroll
        for (int nt = 0; nt < 8; ++nt) acc2[mt][nt] = zero;

#pragma unroll
    for (int kt = 0; kt < 4; ++kt) {
        short8 a0 = *reinterpret_cast<const short8*>(&sA[(m0 + mr) * LDA + kt * 32 + q * 8]);
        short8 a1 = *reinterpret_cast<const short8*>(&sA[(m0 + 16 + mr) * LDA + kt * 32 + q * 8]);
#pragma unroll
        for (int nt = 0; nt < 8; ++nt) {
            short8 b = *reinterpret_cast<const short8*>(&sB[(nt * 16 + mr) * LDA + kt * 32 + q * 8]);
            acc2[0][nt] = __builtin_amdgcn_mfma_f32_16x16x32_bf16(a0, b, acc2[0][nt], 0, 0, 0);
            acc2[1][nt] = __builtin_amdgcn_mfma_f32_16x16x32_bf16(a1, b, acc2[1][nt], 0, 0, 0);
        }
    }
    __syncthreads(); // stage-2 LDS reads done; reuse sA/sB as output staging

    unsigned char* sG = (unsigned char*)sA;     // [128][64] fp8
    unsigned short* sS = (unsigned short*)sB;   // [128][64] bf16
#pragma unroll
    for (int mt = 0; mt < 2; ++mt)
#pragma unroll
        for (int nt = 0; nt < 8; ++nt)
#pragma unroll
            for (int j = 0; j < 4; ++j) {
                int row = m0 + mt * 16 + q * 4 + j;
                int col = nt * 16 + mr;
                float v = acc2[mt][nt][j];
                if (col < 64) sG[row * 64 + col] = f_to_fp8(v);
                else          sS[row * 64 + (col - 64)] = bfbits(v);
            }
    __syncthreads();
    const unsigned* sGu = (const unsigned*)sG;
    for (int i = tid; i < 128 * 16; i += 256) {
        int r = i >> 4, node = base + r;
        if (node < N) G8[node * 16 + (i & 15)] = sGu[i];
    }
    const unsigned* sSu = (const unsigned*)sS;
    for (int i = tid; i < 128 * 32; i += 256) {
        int r = i >> 5, node = base + r;
        if (node < N) S2u[node * 32 + (i & 31)] = sSu[i];
    }
}

// ---------------- gather-mean of G(fp8) + FC + sigmoid ----------------
__global__ __launch_bounds__(256) void agg2fc_kernel(
    const unsigned* __restrict__ G8, const int* __restrict__ row_ptr,
    const int* __restrict__ srcs, const unsigned* __restrict__ S2u,
    const float* __restrict__ b2, const float* __restrict__ Wfc,
    const float* __restrict__ bfc, float* __restrict__ out, int N)
{
    int g = blockIdx.x * 256 + threadIdx.x;
    int node = g >> 6;
    if (node >= N) return;
    int lane = g & 63, ql = lane & 15, quarter = lane >> 4;
    int s0 = row_ptr[node], s1 = row_ptr[node + 1];
    float a0 = 0.f, a1 = 0.f, a2 = 0.f, a3 = 0.f;
    for (int e = s0; e < s1; e += 16) {
#pragma unroll
        for (int k = 0; k < 4; ++k) {
            int ek = e + quarter + 4 * k;
            bool valid = ek < s1;
            int src = srcs[valid ? ek : 0];
            unsigned u = G8[src * 16 + ql];
            if (valid) {
                f32x2 lo = __builtin_amdgcn_cvt_pk_f32_fp8((int)u, false);
                f32x2 hi = __builtin_amdgcn_cvt_pk_f32_fp8((int)u, true);
                a0 += lo[0]; a1 += lo[1]; a2 += hi[0]; a3 += hi[1];
            }
        }
    }
    a0 += __shfl_xor(a0, 16); a0 += __shfl_xor(a0, 32);
    a1 += __shfl_xor(a1, 16); a1 += __shfl_xor(a1, 32);
    a2 += __shfl_xor(a2, 16); a2 += __shfl_xor(a2, 32);
    a3 += __shfl_xor(a3, 16); a3 += __shfl_xor(a3, 32);
    int deg = s1 - s0;
    float scale = deg > 0 ? 1.f / (float)deg : 0.f;
    uint2 s2p = ((const uint2*)(S2u + (size_t)node * 32))[ql];
    float4 b4 = ((const float4*)b2)[ql];
    float4 w4 = ((const float4*)Wfc)[ql];
    float z = fmaxf(a0 * scale + bflo(s2p.x) + b4.x, 0.f) * w4.x
            + fmaxf(a1 * scale + bfhi(s2p.x) + b4.y, 0.f) * w4.y
            + fmaxf(a2 * scale + bflo(s2p.y) + b4.z, 0.f) * w4.z
            + fmaxf(a3 * scale + bfhi(s2p.y) + b4.w, 0.f) * w4.w;
    z += __shfl_xor(z, 1); z += __shfl_xor(z, 2);
    z += __shfl_xor(z, 4); z += __shfl_xor(z, 8);
    if (lane == 0) out[node] = 1.f / (1.f + __expf(-(z + bfc[0])));
}

// ---------------- launch ----------------
static inline size_t align_up(size_t v, size_t a) { return (v + a - 1) & ~(a - 1); }

extern "C" void kernel_launch(void* const* d_in, const int* in_sizes, int n_in,
                              void* d_out, int out_size, void* d_ws, size_t ws_size,
                              hipStream_t stream) {
    const float* x   = (const float*)d_in[0];
    const int*   ei  = (const int*)d_in[1];
    const float* W1l = (const float*)d_in[2];
    const float* b1  = (const float*)d_in[3];
    const float* W1r = (const float*)d_in[4];
    const float* W2l = (const float*)d_in[5];
    const float* b2  = (const float*)d_in[6];
    const float* W2r = (const float*)d_in[7];
    const float* Wfc = (const float*)d_in[8];
    const float* bfc = (const float*)d_in[9];
    float* out = (float*)d_out;

    const int N = in_sizes[0] / IN_C;   // 100000
    const int E = in_sizes[1] / 2;      // 1600000
    const int NBUCK = (N + BR - 1) / BR;        // 196
    const int EPB = (E + P1B - 1) / P1B;        // 6250

    char* ws = (char*)d_ws;
    size_t o = 0;
    int* row_ptr  = (int*)(ws + o); o = align_up(o + (size_t)(N + 1) * 4, 256);
    int* srcs     = (int*)(ws + o); o = align_up(o + (size_t)E * 4, 256);
    int* cnt      = (int*)(ws + o); o = align_up(o + (size_t)P1B * 256 * 4, 256);
    int* gofs     = (int*)(ws + o); o = align_up(o + (size_t)P1B * 256 * 4, 256);
    int* bb       = (int*)(ws + o); o = align_up(o + 257 * 4, 256);
    // part (E*8 = 12.8 MB) aliases S2u (N*128 B = 12.8 MB): part dead after csr.
    size_t part_off = o;
    size_t sz1 = (size_t)E * 8, sz2 = (size_t)N * 128;
    o = align_up(part_off + (sz1 > sz2 ? sz1 : sz2), 256);
    int2* part = (int2*)(ws + part_off);
    unsigned* S2u = (unsigned*)(ws + part_off);
    unsigned* xbu = (unsigned*)(ws + o); o = align_up(o + (size_t)N * 32 * 4, 256);
    unsigned* xf8 = (unsigned*)(ws + o); o = align_up(o + (size_t)N * 16 * 4, 256);
    unsigned* M1u = (unsigned*)(ws + o); o = align_up(o + (size_t)N * 32 * 4, 256);
    unsigned* G8  = (unsigned*)(ws + o); o = align_up(o + (size_t)N * 16 * 4, 256);

    count_kernel<<<P1B, 256, 0, stream>>>(ei, cnt, (const float4*)x, xbu, xf8,
                                          N * 16, E, EPB, NBUCK);
    offs_kernel<<<1, 256, 0, stream>>>(cnt, gofs, bb, row_ptr, N, E, NBUCK);
    scatter_kernel<<<P1B, 256, 0, stream>>>(ei, gofs, part, E, EPB, NBUCK);
    csr_kernel<<<NBUCK, 256, 0, stream>>>(part, bb, row_ptr, srcs, N);

    int gwb = (N * 64 + 255) / 256;
    agg1_kernel<<<gwb, 256, 0, stream>>>(xf8, row_ptr, srcs, M1u, N);
    dense_kernel<<<(N + 127) / 128, 256, 0, stream>>>(
        (const unsigned short*)M1u, (const unsigned short*)xbu,
        W1l, b1, W1r, W2l, W2r, G8, S2u, N);
    agg2fc_kernel<<<gwb, 256, 0, stream>>>(G8, row_ptr, srcs, S2u, b2, Wfc, bfc, out, N);
}